// Round 8
// baseline (162.354 us; speedup 1.0000x reference)
//
#include <hip/hip_runtime.h>
#include <math.h>

#define F 128
#define NTOT 2080
#define CN 2048
#define AN 16
#define NA 17   // max agents (step>0)
#define CHK 128 // cities per chunk (k35/k6)
#define NCHK 16 // CN/CHK

__device__ __forceinline__ float wmax(float v){
  #pragma unroll
  for(int m=32;m;m>>=1) v = fmaxf(v, __shfl_xor(v, m, 64));
  return v;
}
__device__ __forceinline__ float wsum(float v){
  #pragma unroll
  for(int m=32;m;m>>=1) v += __shfl_xor(v, m, 64);
  return v;
}

// K0t: tiled transposes of Wg(128x512), Wc(384x256), Wp(128x128), Wa(128x384)
__global__ __launch_bounds__(256) void k0t_transpose(
      const float* __restrict__ Wg, const float* __restrict__ Wc,
      const float* __restrict__ Wp, const float* __restrict__ Wa,
      float* __restrict__ WgT, float* __restrict__ WcT,
      float* __restrict__ WpT, float* __restrict__ WaT){
  __shared__ float tile[32][33];
  const int z = blockIdx.z;
  const float* src; float* dst; int R, C;
  if(z==0){ src=Wg; dst=WgT; R=128; C=512; }
  else if(z==1){ src=Wc; dst=WcT; R=384; C=256; }
  else if(z==2){ src=Wp; dst=WpT; R=128; C=128; }
  else { src=Wa; dst=WaT; R=128; C=384; }
  const int c0 = blockIdx.x*32, r0 = blockIdx.y*32;
  if(c0>=C || r0>=R) return;
  const int tx = threadIdx.x&31, ty = threadIdx.x>>5;   // 32x8
  #pragma unroll
  for(int rr=0;rr<4;rr++)
    tile[ty+rr*8][tx] = src[(size_t)(r0+ty+rr*8)*C + c0 + tx];
  __syncthreads();
  #pragma unroll
  for(int rr=0;rr<4;rr++)
    dst[(size_t)(c0+ty+rr*8)*R + r0 + tx] = tile[tx][ty+rr*8];
}

// K0a: Wpy = Wp @ Wcy2   (Wpy[k,i] = sum_j Wp[k,j]*Wc[128+j, 128+i])
__global__ __launch_bounds__(128) void k0a_wpy(const float* __restrict__ Wp, const float* __restrict__ Wc,
                                               float* __restrict__ Wpy){
  const int k = blockIdx.x, i = threadIdx.x;
  float acc = 0.f;
  const float* wp = Wp + (size_t)k*F;
  for(int j=0;j<F;j++) acc += wp[j]*Wc[(size_t)(128+j)*256 + 128 + i];
  Wpy[k*F+i] = acc;
}

// K0b: M1 = Wcz2^T @ Wpy  (M1[jc,i] = sum_k Wc[256+k, 128+jc]*Wpy[k,i])
__global__ __launch_bounds__(128) void k0b_m1(const float* __restrict__ Wc, const float* __restrict__ Wpy,
                                              float* __restrict__ M1){
  const int jc = blockIdx.x, i = threadIdx.x;
  float acc = 0.f;
  for(int k=0;k<F;k++) acc += Wc[(size_t)(256+k)*256 + 128 + jc]*Wpy[k*F+i];
  M1[jc*F+i] = acc;
}

// K1: per (b, j-group of 4): one wave per feature row, segment max/mean over N=2080
__global__ __launch_bounds__(256) void k1_reduce(const float* __restrict__ nf,
                                                 float* __restrict__ glb, float* __restrict__ ave){
  const int jg = blockIdx.x, b = blockIdx.y;
  const int w = threadIdx.x>>6, lane = threadIdx.x&63;
  const int j = jg*4 + w;
  const float4* row = (const float4*)(nf + (size_t)(b*F + j)*NTOT);
  float cmax=-INFINITY, csum=0.f, smax=-INFINITY, ssum=0.f, emax=-INFINITY, esum=0.f;
  for(int n4 = lane; n4 < 520; n4 += 64){
    float4 v = row[n4];
    float mx = fmaxf(fmaxf(v.x,v.y), fmaxf(v.z,v.w));
    float sm = (v.x+v.y)+(v.z+v.w);
    if(n4 < 512){ cmax=fmaxf(cmax,mx); csum+=sm; }
    else if(n4 < 516){ smax=fmaxf(smax,mx); ssum+=sm; }
    else { emax=fmaxf(emax,mx); esum+=sm; }
  }
  cmax=wmax(cmax); csum=wsum(csum); smax=wmax(smax); ssum=wsum(ssum); emax=wmax(emax); esum=wsum(esum);
  if(lane==0){
    const int gb = b*4*F;
    glb[gb + j]       = fmaxf(cmax, fmaxf(smax,emax));
    glb[gb + F + j]   = cmax;
    glb[gb + 2*F + j] = smax;
    glb[gb + 3*F + j] = emax;
    float tS = csum+ssum+esum;
    ave[gb + j]       = tS / 2080.f;
    ave[gb + F + j]   = csum / 2048.f;
    ave[gb + 2*F + j] = ssum / 16.f;
    ave[gb + 3*F + j] = esum / 16.f;
  }
}

// K2a: per-batch: deglb/fa (WgT, thread-per-j), cvec (WcT), cpy (WpT) + vz, czc, szc
__global__ __launch_bounds__(256) void k2a_prep(
    const float* __restrict__ WgT, const float* __restrict__ bg,
    const float* __restrict__ WcT, const float* __restrict__ Wc, const float* __restrict__ bc,
    const float* __restrict__ WpT, const float* __restrict__ bp,
    const float* __restrict__ Wpy,
    const float* __restrict__ glb, const float* __restrict__ ave,
    float* __restrict__ deglb_g, float* __restrict__ fa_g, float* __restrict__ cx,
    float* __restrict__ czc, float* __restrict__ vz, float* __restrict__ szc){
  const int b = blockIdx.x, tid = threadIdx.x;
  __shared__ float glb_s[512], ave_s[512];
  __shared__ float deglb_s[F], cvec_s[3*F], cpy_s[F];
  for(int i=tid;i<512;i+=256){ glb_s[i]=glb[b*512+i]; ave_s[i]=ave[b*512+i]; }
  __syncthreads();
  {
    const int j = tid&127;
    const float* src = (tid<128)? glb_s : ave_s;
    float a0=0.f,a1=0.f,a2=0.f,a3=0.f;
    for(int k=0;k<512;k+=4){
      a0 += WgT[(size_t)(k+0)*128+j]*src[k+0];
      a1 += WgT[(size_t)(k+1)*128+j]*src[k+1];
      a2 += WgT[(size_t)(k+2)*128+j]*src[k+2];
      a3 += WgT[(size_t)(k+3)*128+j]*src[k+3];
    }
    float d = (a0+a1)+(a2+a3) + bg[j];
    if(tid<128){ deglb_s[j]=d; deglb_g[b*F+j]=d; }
    else fa_g[b*F+j]=d;
  }
  __syncthreads();
  for(int i=tid;i<3*F;i+=256){
    float a0=0.f,a1=0.f,a2=0.f,a3=0.f;
    for(int k=0;k<F;k+=4){
      a0 += WcT[(size_t)(k+0)*384+i]*deglb_s[k+0];
      a1 += WcT[(size_t)(k+1)*384+i]*deglb_s[k+1];
      a2 += WcT[(size_t)(k+2)*384+i]*deglb_s[k+2];
      a3 += WcT[(size_t)(k+3)*384+i]*deglb_s[k+3];
    }
    float v = (a0+a1)+(a2+a3) + bc[i];
    cvec_s[i]=v;
    if(i<F) cx[b*F+i]=v;
  }
  __syncthreads();
  if(tid<128){
    const int j = tid;
    float a0=0.f,a1=0.f,a2=0.f,a3=0.f;
    for(int k=0;k<F;k+=4){
      a0 += WpT[(size_t)(k+0)*128+j]*cvec_s[128+k+0];
      a1 += WpT[(size_t)(k+1)*128+j]*cvec_s[128+k+1];
      a2 += WpT[(size_t)(k+2)*128+j]*cvec_s[128+k+2];
      a3 += WpT[(size_t)(k+3)*128+j]*cvec_s[128+k+3];
    }
    cpy_s[j] = (a0+a1)+(a2+a3) + bp[j];
  } else {
    const int j = tid-128;
    float a0=0.f,a1=0.f,a2=0.f,a3=0.f;
    for(int k=0;k<F;k+=4){
      a0 += Wpy[(size_t)(k+0)*128+j]*cvec_s[256+k+0];
      a1 += Wpy[(size_t)(k+1)*128+j]*cvec_s[256+k+1];
      a2 += Wpy[(size_t)(k+2)*128+j]*cvec_s[256+k+2];
      a3 += Wpy[(size_t)(k+3)*128+j]*cvec_s[256+k+3];
    }
    vz[b*F+j] = (a0+a1)+(a2+a3);
  }
  __syncthreads();
  if(tid<128){
    const int j = tid;
    float a0=0.f,a1=0.f,a2=0.f,a3=0.f;
    for(int k=0;k<F;k+=4){
      a0 += Wc[(size_t)(256+k+0)*256 + 128 + j]*cpy_s[k+0];
      a1 += Wc[(size_t)(256+k+1)*256 + 128 + j]*cpy_s[k+1];
      a2 += Wc[(size_t)(256+k+2)*256 + 128 + j]*cpy_s[k+2];
      a3 += Wc[(size_t)(256+k+3)*256 + 128 + j]*cpy_s[k+3];
    }
    czc[b*F+j] = (a0+a1)+(a2+a3);
  } else if(tid<192){
    const int lane = tid-128;
    float p = cpy_s[lane]*cvec_s[256+lane] + cpy_s[64+lane]*cvec_s[256+64+lane];
    p = wsum(p);
    if(lane==0) szc[b]=p;
  }
}

// K2c: per (agent a, batch b): af (WaT, thread-per-j), afx, sx
__global__ __launch_bounds__(256) void k2c_agents(
    const float* __restrict__ nf, const float* __restrict__ WaT, const float* __restrict__ ba,
    const float* __restrict__ Wc,
    const float* __restrict__ deglb_g, const float* __restrict__ fa_g, const float* __restrict__ cx,
    float* __restrict__ afx, float* __restrict__ sx){
  const int a = blockIdx.x, b = blockIdx.y, tid = threadIdx.x;
  __shared__ float src_s[384];
  __shared__ float af_s[F], cx_s[F];
  if(tid<128){ src_s[tid] = deglb_g[b*F+tid]; cx_s[tid]=cx[b*F+tid]; }
  else if(a<16){
    const int j = tid-128;
    src_s[128+j] = nf[(size_t)(b*F+j)*NTOT + CN + a];
    src_s[256+j] = nf[(size_t)(b*F+j)*NTOT + CN + AN + a];
  }
  __syncthreads();
  if(a<16){
    if(tid<128){
      const int j = tid;
      float a0=0.f,a1=0.f,a2=0.f,a3=0.f;
      for(int k=0;k<384;k+=4){
        a0 += WaT[(size_t)(k+0)*128+j]*src_s[k+0];
        a1 += WaT[(size_t)(k+1)*128+j]*src_s[k+1];
        a2 += WaT[(size_t)(k+2)*128+j]*src_s[k+2];
        a3 += WaT[(size_t)(k+3)*128+j]*src_s[k+3];
      }
      af_s[j] = (a0+a1)+(a2+a3) + ba[j];
    }
  } else if(tid<128){
    af_s[tid] = fa_g[b*F+tid];
  }
  __syncthreads();
  if(tid<128){
    const int j = tid;
    float a0=0.f,a1=0.f,a2=0.f,a3=0.f;
    for(int i=0;i<F;i+=4){
      a0 += af_s[i+0]*Wc[(size_t)(i+0)*256 + 128 + j];
      a1 += af_s[i+1]*Wc[(size_t)(i+1)*256 + 128 + j];
      a2 += af_s[i+2]*Wc[(size_t)(i+2)*256 + 128 + j];
      a3 += af_s[i+3]*Wc[(size_t)(i+3)*256 + 128 + j];
    }
    afx[((size_t)b*NA+a)*F + j] = (a0+a1)+(a2+a3);
  } else if(tid<192){
    const int lane = tid-128;
    float p = af_s[lane]*cx_s[lane] + af_s[64+lane]*cx_s[64+lane];
    p = wsum(p);
    if(lane==0) sx[b*NA+a]=p;
  }
}

// K35: fused scores + chunk softmax + t-accum. Register-tiled:
// phase1: 2 cities x 17 agents x K-quarter per thread; phase4: 2 features x 9 agents x g-parity.
__global__ __launch_bounds__(256) void k35_flash(const float* __restrict__ nf,
      const float* __restrict__ afx, const float* __restrict__ sx,
      float* __restrict__ pmax, float* __restrict__ psum, float* __restrict__ tpart){
  const int b = blockIdx.y, tid = threadIdx.x;
  const int chunk = blockIdx.x, c0 = chunk*CHK;
  __shared__ float afx_s[NA*F];     // also reused as pt (phase-4 partial combine)
  __shared__ float sx_s[NA];
  __shared__ float at_s[NA*CHK];
  __shared__ float4 nf4_s[F*8];
  __shared__ float red_s[4][NA], red2_s[4][NA];
  for(int o=tid;o<NA*F;o+=256) afx_s[o]=afx[(size_t)b*NA*F+o];
  if(tid<NA) sx_s[tid]=sx[b*NA+tid];
  __syncthreads();
  const int kq = tid>>6;       // K-quarter (= wave id)
  const int ct = tid&63;       // city pair index: cities 2ct, 2ct+1
  const int lane = tid&63, w = tid>>6;
  // ---- phase 1: 2-city x 17-agent x 32-K dot partials ----
  float2 acc[NA];
  #pragma unroll
  for(int a=0;a<NA;a++){ acc[a].x=0.f; acc[a].y=0.f; }
  {
    const float* base = nf + (size_t)b*F*NTOT + (size_t)(kq*32)*NTOT + c0 + 2*ct;
    #pragma unroll 2
    for(int q=0;q<8;q++){
      float2 l0 = *(const float2*)(base + (size_t)(q*4+0)*NTOT);
      float2 l1 = *(const float2*)(base + (size_t)(q*4+1)*NTOT);
      float2 l2 = *(const float2*)(base + (size_t)(q*4+2)*NTOT);
      float2 l3 = *(const float2*)(base + (size_t)(q*4+3)*NTOT);
      #pragma unroll
      for(int a=0;a<NA;a++){
        float4 wv = *(const float4*)&afx_s[a*F + kq*32 + q*4];
        acc[a].x += wv.x*l0.x + wv.y*l1.x + wv.z*l2.x + wv.w*l3.x;
        acc[a].y += wv.x*l0.y + wv.y*l1.y + wv.z*l2.y + wv.w*l3.y;
      }
    }
  }
  // serial 4-step combine of K-quarters into at_s
  for(int k=0;k<4;k++){
    __syncthreads();
    if(kq==k){
      #pragma unroll
      for(int a=0;a<NA;a++){
        float2* p = (float2*)&at_s[a*CHK + 2*ct];
        if(k==0){ *p = acc[a]; }
        else { float2 v = *p; v.x += acc[a].x; v.y += acc[a].y; *p = v; }
      }
    }
  }
  __syncthreads();
  // ---- softmax over the chunk (agent-split across halves) ----
  const int cl = tid&127;
  const int hh = tid>>7;            // 0: agents 0..8, 1: agents 9..16
  const int aBeg = hh? 9:0;
  const float scale = 0.088388347648318447f;
  float sc[9];
  #pragma unroll
  for(int a2=0;a2<9;a2++){
    const int a = aBeg+a2;
    if(a<NA){
      sc[a2] = (at_s[a*CHK+cl] + sx_s[a])*scale;
      float mx = wmax(sc[a2]);
      if(lane==0) red_s[w][a]=mx;
    }
  }
  __syncthreads();
  #pragma unroll
  for(int a2=0;a2<9;a2++){
    const int a = aBeg+a2;
    if(a<NA){
      float m = fmaxf(red_s[hh*2][a], red_s[hh*2+1][a]);
      float e = __expf(sc[a2]-m);
      at_s[a*CHK+cl] = e;
      float s = wsum(e);
      if(lane==0) red2_s[w][a]=s;
    }
  }
  __syncthreads();
  if(tid<NA){
    const int base = (tid<9)? 0 : 2;
    pmax[(b*NA+tid)*NCHK + chunk] = fmaxf(red_s[base][tid], red_s[base+1][tid]);
    psum[(b*NA+tid)*NCHK + chunk] = red2_s[base][tid] + red2_s[base+1][tid];
  }
  // ---- phase 4: tpart[a][i] = sum_c e[a,c]*nf[i,c], 2 features x 9 agents per thread ----
  const int i1 = tid&63;            // feature rows i1 and i1+64
  const int g2 = (tid>>6)&1;        // g-parity split
  const int h  = tid>>7;            // agent half, A0 = h*8 (overlap at agent 8)
  const int A0 = h*8;
  float ta0[9], ta1[9];
  #pragma unroll
  for(int a=0;a<9;a++){ ta0[a]=0.f; ta1[a]=0.f; }
  for(int s4=0;s4<4;s4++){
    const int csl = s4*32, cs = c0 + csl;
    __syncthreads();
    for(int idx=tid; idx<F*8; idx+=256){
      const int ii=idx>>3, g=idx&7;
      nf4_s[ii*8 + (g^(ii&7))] = *(const float4*)(nf + (size_t)(b*F+ii)*NTOT + cs + g*4);
    }
    __syncthreads();
    #pragma unroll
    for(int gg=0; gg<4; gg++){
      const int g = gg*2 + g2;
      float4 v0 = nf4_s[i1*8 + (g^(i1&7))];
      float4 v1 = nf4_s[(i1+64)*8 + (g^(i1&7))];
      #pragma unroll
      for(int a=0;a<9;a++){
        float4 wv = *(const float4*)&at_s[(A0+a)*CHK + csl + g*4];
        ta0[a] += wv.x*v0.x + wv.y*v0.y + wv.z*v0.z + wv.w*v0.w;
        ta1[a] += wv.x*v1.x + wv.y*v1.y + wv.z*v1.z + wv.w*v1.w;
      }
    }
  }
  // combine g-parity partials through pt (aliases afx_s; phase1 done with it)
  float* pt = afx_s;
  __syncthreads();
  if(g2==1){
    #pragma unroll
    for(int a=0;a<9;a++){
      pt[(A0+a)*F + i1]      = ta0[a];
      pt[(A0+a)*F + i1 + 64] = ta1[a];
    }
  }
  __syncthreads();
  if(g2==0){
    float* dst = tpart + (size_t)chunk*64*NA*F + (size_t)b*NA*F;
    #pragma unroll
    for(int a=0;a<9;a++){
      if(h==0 || a>0){
        dst[(A0+a)*F + i1]      = ta0[a] + pt[(A0+a)*F + i1];
        dst[(A0+a)*F + i1 + 64] = ta1[a] + pt[(A0+a)*F + i1 + 64];
      }
    }
  }
}

// K5c: per (b,a): combine 16 chunks with rescale; tn; afz = M1@tn + czc; sz = tn.vz + szc
__global__ __launch_bounds__(128) void k5c_final(const float* __restrict__ M1,
      const float* __restrict__ tpart, const float* __restrict__ pmax, const float* __restrict__ psum,
      const float* __restrict__ czc, const float* __restrict__ vz, const float* __restrict__ szc,
      float* __restrict__ afz, float* __restrict__ szv){
  const int a = blockIdx.x, b = blockIdx.y, tid = threadIdx.x;
  __shared__ float tn_s[F];
  const float* pm = pmax + (b*NA+a)*NCHK;
  const float* ps = psum + (b*NA+a)*NCHK;
  float M=-INFINITY;
  #pragma unroll
  for(int k=0;k<NCHK;k++) M = fmaxf(M, pm[k]);
  float w[NCHK]; float rs=0.f;
  #pragma unroll
  for(int k=0;k<NCHK;k++){ w[k]=__expf(pm[k]-M); rs += ps[k]*w[k]; }
  float s = 0.f;
  #pragma unroll
  for(int k=0;k<NCHK;k++) s += tpart[(size_t)k*64*NA*F + ((size_t)b*NA+a)*F + tid]*w[k];
  tn_s[tid] = s / rs;
  __syncthreads();
  float acc = 0.f;
  const float* m = M1 + (size_t)tid*F;
  for(int i=0;i<F;i++) acc += m[i]*tn_s[i];
  afz[((size_t)b*NA+a)*F + tid] = acc + czc[b*F+tid];
  float p = tn_s[tid]*vz[b*F+tid];
  p = wsum(p);
  __shared__ float red[2];
  if((tid&63)==0) red[tid>>6]=p;
  __syncthreads();
  if(tid==0) szv[b*NA+a] = red[0]+red[1] + szc[b];
}

// K6: logits + tanh + agent softmax. Register-tiled phase 1 like k35, 128-thread epilogue.
__global__ __launch_bounds__(256) void k6_out(const float* __restrict__ nf, const float* __restrict__ afz,
      const float* __restrict__ szv, const int* __restrict__ step, float* __restrict__ out){
  const int b = blockIdx.y, tid = threadIdx.x;
  const int chunk = blockIdx.x, c0 = chunk*CHK;
  __shared__ float afz_s[NA*F]; __shared__ float sz_s[NA];
  __shared__ float sc_s[NA*CHK];
  for(int o=tid;o<NA*F;o+=256) afz_s[o]=afz[(size_t)b*NA*F+o];
  if(tid<NA) sz_s[tid]=szv[b*NA+tid];
  __syncthreads();
  const int kq = tid>>6, ct = tid&63;
  float2 acc[NA];
  #pragma unroll
  for(int a=0;a<NA;a++){ acc[a].x=0.f; acc[a].y=0.f; }
  {
    const float* base = nf + (size_t)b*F*NTOT + (size_t)(kq*32)*NTOT + c0 + 2*ct;
    #pragma unroll 2
    for(int q=0;q<8;q++){
      float2 l0 = *(const float2*)(base + (size_t)(q*4+0)*NTOT);
      float2 l1 = *(const float2*)(base + (size_t)(q*4+1)*NTOT);
      float2 l2 = *(const float2*)(base + (size_t)(q*4+2)*NTOT);
      float2 l3 = *(const float2*)(base + (size_t)(q*4+3)*NTOT);
      #pragma unroll
      for(int a=0;a<NA;a++){
        float4 wv = *(const float4*)&afz_s[a*F + kq*32 + q*4];
        acc[a].x += wv.x*l0.x + wv.y*l1.x + wv.z*l2.x + wv.w*l3.x;
        acc[a].y += wv.x*l0.y + wv.y*l1.y + wv.z*l2.y + wv.w*l3.y;
      }
    }
  }
  for(int k=0;k<4;k++){
    __syncthreads();
    if(kq==k){
      #pragma unroll
      for(int a=0;a<NA;a++){
        float2* p = (float2*)&sc_s[a*CHK + 2*ct];
        if(k==0){ *p = acc[a]; }
        else { float2 v = *p; v.x += acc[a].x; v.y += acc[a].y; *p = v; }
      }
    }
  }
  __syncthreads();
  if(tid<128){
    const int cl = tid;
    const int A = (step[0] > 0) ? NA : AN;
    const float scale = 0.088388347648318447f;
    float l[NA];
    #pragma unroll
    for(int a=0;a<NA;a++)
      l[a] = tanhf((sc_s[a*CHK+cl] + sz_s[a])*scale)*10.f;
    const bool f17 = (A==NA);
    float m = l[0];
    #pragma unroll
    for(int a=1;a<AN;a++) m = fmaxf(m,l[a]);
    if(f17) m = fmaxf(m,l[16]);
    float ssum=0.f;
    #pragma unroll
    for(int a=0;a<AN;a++){ float e=__expf(l[a]-m); l[a]=e; ssum+=e; }
    float e16=__expf(l[16]-m);
    if(f17){ ssum+=e16; }
    const float inv = 1.f/ssum;
    float* op = out + (size_t)(b*CN + c0 + cl)*A;
    #pragma unroll
    for(int a=0;a<AN;a++) op[a]=l[a]*inv;
    if(f17) op[16]=e16*inv;
  }
}

extern "C" void kernel_launch(void* const* d_in, const int* in_sizes, int n_in,
                              void* d_out, int out_size, void* d_ws, size_t ws_size,
                              hipStream_t stream){
  const float* nf = (const float*)d_in[0];
  const float* Wg = (const float*)d_in[1];
  const float* bg = (const float*)d_in[2];
  const float* Wc = (const float*)d_in[3];
  const float* bc = (const float*)d_in[4];
  const float* Wa = (const float*)d_in[5];
  const float* ba = (const float*)d_in[6];
  const float* Wp = (const float*)d_in[7];
  const float* bp = (const float*)d_in[8];
  const int*  step = (const int*)d_in[9];
  float* out = (float*)d_out;

  float* ws = (float*)d_ws;
  float* glb     = ws;                    // 64*512
  float* ave     = glb + 64*512;          // 64*512
  float* afx     = ave + 64*512;          // 64*17*128
  float* sx      = afx + 64*NA*F;         // 64*17
  float* Wpy     = sx + 64*NA;            // 128*128
  float* M1      = Wpy + F*F;             // 128*128
  float* czc     = M1 + F*F;              // 64*128
  float* vz      = czc + 64*F;            // 64*128
  float* szc     = vz + 64*F;             // 64
  float* pmax    = szc + 64;              // 64*17*16
  float* psum    = pmax + 64*NA*NCHK;     // 64*17*16
  float* deglb_g = psum + 64*NA*NCHK;     // 64*128
  float* fa_g    = deglb_g + 64*F;        // 64*128
  float* cx      = fa_g + 64*F;           // 64*128
  float* WgT     = cx + 64*F;             // 512*128
  float* WcT     = WgT + 512*F;           // 256*384
  float* WpT     = WcT + 256*384;         // 128*128
  float* WaT     = WpT + F*F;             // 384*128
  float* tpart   = WaT + 384*F;           // 16*64*17*128
  float* afz     = tpart + (size_t)NCHK*64*NA*F;  // 64*17*128
  float* szv     = afz + 64*NA*F;         // 64*17

  k0t_transpose<<<dim3(16,12,4),256,0,stream>>>(Wg,Wc,Wp,Wa, WgT,WcT,WpT,WaT);
  k0a_wpy<<<F,F,0,stream>>>(Wp, Wc, Wpy);
  k0b_m1<<<F,F,0,stream>>>(Wc, Wpy, M1);
  k1_reduce<<<dim3(32,64),256,0,stream>>>(nf, glb, ave);
  k2a_prep<<<64,256,0,stream>>>(WgT,bg, WcT,Wc,bc, WpT,bp, Wpy, glb,ave, deglb_g,fa_g,cx, czc,vz,szc);
  k2c_agents<<<dim3(NA,64),256,0,stream>>>(nf, WaT,ba,Wc, deglb_g,fa_g,cx, afx,sx);
  k35_flash<<<dim3(NCHK,64),256,0,stream>>>(nf, afx, sx, pmax, psum, tpart);
  k5c_final<<<dim3(NA,64),128,0,stream>>>(M1, tpart, pmax, psum, czc, vz, szc, afz, szv);
  k6_out<<<dim3(NCHK,64),256,0,stream>>>(nf, afz, szv, step, out);
}

// Round 9
// 160.122 us; speedup vs baseline: 1.0139x; 1.0139x over previous
//
#include <hip/hip_runtime.h>
#include <math.h>

#define F 128
#define NTOT 2080
#define CN 2048
#define AN 16
#define NA 17   // max agents (step>0)
#define CHK 256 // cities per chunk (k35/k6)
#define NCHK 8  // CN/CHK

__device__ __forceinline__ float wmax(float v){
  #pragma unroll
  for(int m=32;m;m>>=1) v = fmaxf(v, __shfl_xor(v, m, 64));
  return v;
}
__device__ __forceinline__ float wsum(float v){
  #pragma unroll
  for(int m=32;m;m>>=1) v += __shfl_xor(v, m, 64);
  return v;
}

// K0t: tiled transposes of Wg(128x512), Wc(384x256), Wp(128x128), Wa(128x384)
__global__ __launch_bounds__(256) void k0t_transpose(
      const float* __restrict__ Wg, const float* __restrict__ Wc,
      const float* __restrict__ Wp, const float* __restrict__ Wa,
      float* __restrict__ WgT, float* __restrict__ WcT,
      float* __restrict__ WpT, float* __restrict__ WaT){
  __shared__ float tile[32][33];
  const int z = blockIdx.z;
  const float* src; float* dst; int R, C;
  if(z==0){ src=Wg; dst=WgT; R=128; C=512; }
  else if(z==1){ src=Wc; dst=WcT; R=384; C=256; }
  else if(z==2){ src=Wp; dst=WpT; R=128; C=128; }
  else { src=Wa; dst=WaT; R=128; C=384; }
  const int c0 = blockIdx.x*32, r0 = blockIdx.y*32;
  if(c0>=C || r0>=R) return;
  const int tx = threadIdx.x&31, ty = threadIdx.x>>5;   // 32x8
  #pragma unroll
  for(int rr=0;rr<4;rr++)
    tile[ty+rr*8][tx] = src[(size_t)(r0+ty+rr*8)*C + c0 + tx];
  __syncthreads();
  #pragma unroll
  for(int rr=0;rr<4;rr++)
    dst[(size_t)(c0+ty+rr*8)*R + r0 + tx] = tile[tx][ty+rr*8];
}

// K0a: Wpy = Wp @ Wcy2
__global__ __launch_bounds__(128) void k0a_wpy(const float* __restrict__ Wp, const float* __restrict__ Wc,
                                               float* __restrict__ Wpy){
  const int k = blockIdx.x, i = threadIdx.x;
  float acc = 0.f;
  const float* wp = Wp + (size_t)k*F;
  for(int j=0;j<F;j++) acc += wp[j]*Wc[(size_t)(128+j)*256 + 128 + i];
  Wpy[k*F+i] = acc;
}

// K0b: M1 = Wcz2^T @ Wpy
__global__ __launch_bounds__(128) void k0b_m1(const float* __restrict__ Wc, const float* __restrict__ Wpy,
                                              float* __restrict__ M1){
  const int jc = blockIdx.x, i = threadIdx.x;
  float acc = 0.f;
  for(int k=0;k<F;k++) acc += Wc[(size_t)(256+k)*256 + 128 + jc]*Wpy[k*F+i];
  M1[jc*F+i] = acc;
}

// K1: per (b, j-group of 4): one wave per feature row, segment max/mean over N=2080
__global__ __launch_bounds__(256) void k1_reduce(const float* __restrict__ nf,
                                                 float* __restrict__ glb, float* __restrict__ ave){
  const int jg = blockIdx.x, b = blockIdx.y;
  const int w = threadIdx.x>>6, lane = threadIdx.x&63;
  const int j = jg*4 + w;
  const float4* row = (const float4*)(nf + (size_t)(b*F + j)*NTOT);
  float cmax=-INFINITY, csum=0.f, smax=-INFINITY, ssum=0.f, emax=-INFINITY, esum=0.f;
  for(int n4 = lane; n4 < 520; n4 += 64){
    float4 v = row[n4];
    float mx = fmaxf(fmaxf(v.x,v.y), fmaxf(v.z,v.w));
    float sm = (v.x+v.y)+(v.z+v.w);
    if(n4 < 512){ cmax=fmaxf(cmax,mx); csum+=sm; }
    else if(n4 < 516){ smax=fmaxf(smax,mx); ssum+=sm; }
    else { emax=fmaxf(emax,mx); esum+=sm; }
  }
  cmax=wmax(cmax); csum=wsum(csum); smax=wmax(smax); ssum=wsum(ssum); emax=wmax(emax); esum=wsum(esum);
  if(lane==0){
    const int gb = b*4*F;
    glb[gb + j]       = fmaxf(cmax, fmaxf(smax,emax));
    glb[gb + F + j]   = cmax;
    glb[gb + 2*F + j] = smax;
    glb[gb + 3*F + j] = emax;
    float tS = csum+ssum+esum;
    ave[gb + j]       = tS / 2080.f;
    ave[gb + F + j]   = csum / 2048.f;
    ave[gb + 2*F + j] = ssum / 16.f;
    ave[gb + 3*F + j] = esum / 16.f;
  }
}

// K2a: per-batch small matvecs (transposed weights, thread-per-output)
__global__ __launch_bounds__(256) void k2a_prep(
    const float* __restrict__ WgT, const float* __restrict__ bg,
    const float* __restrict__ WcT, const float* __restrict__ Wc, const float* __restrict__ bc,
    const float* __restrict__ WpT, const float* __restrict__ bp,
    const float* __restrict__ Wpy,
    const float* __restrict__ glb, const float* __restrict__ ave,
    float* __restrict__ deglb_g, float* __restrict__ fa_g, float* __restrict__ cx,
    float* __restrict__ czc, float* __restrict__ vz, float* __restrict__ szc){
  const int b = blockIdx.x, tid = threadIdx.x;
  __shared__ float glb_s[512], ave_s[512];
  __shared__ float deglb_s[F], cvec_s[3*F], cpy_s[F];
  for(int i=tid;i<512;i+=256){ glb_s[i]=glb[b*512+i]; ave_s[i]=ave[b*512+i]; }
  __syncthreads();
  {
    const int j = tid&127;
    const float* src = (tid<128)? glb_s : ave_s;
    float a0=0.f,a1=0.f,a2=0.f,a3=0.f;
    for(int k=0;k<512;k+=4){
      a0 += WgT[(size_t)(k+0)*128+j]*src[k+0];
      a1 += WgT[(size_t)(k+1)*128+j]*src[k+1];
      a2 += WgT[(size_t)(k+2)*128+j]*src[k+2];
      a3 += WgT[(size_t)(k+3)*128+j]*src[k+3];
    }
    float d = (a0+a1)+(a2+a3) + bg[j];
    if(tid<128){ deglb_s[j]=d; deglb_g[b*F+j]=d; }
    else fa_g[b*F+j]=d;
  }
  __syncthreads();
  for(int i=tid;i<3*F;i+=256){
    float a0=0.f,a1=0.f,a2=0.f,a3=0.f;
    for(int k=0;k<F;k+=4){
      a0 += WcT[(size_t)(k+0)*384+i]*deglb_s[k+0];
      a1 += WcT[(size_t)(k+1)*384+i]*deglb_s[k+1];
      a2 += WcT[(size_t)(k+2)*384+i]*deglb_s[k+2];
      a3 += WcT[(size_t)(k+3)*384+i]*deglb_s[k+3];
    }
    float v = (a0+a1)+(a2+a3) + bc[i];
    cvec_s[i]=v;
    if(i<F) cx[b*F+i]=v;
  }
  __syncthreads();
  if(tid<128){
    const int j = tid;
    float a0=0.f,a1=0.f,a2=0.f,a3=0.f;
    for(int k=0;k<F;k+=4){
      a0 += WpT[(size_t)(k+0)*128+j]*cvec_s[128+k+0];
      a1 += WpT[(size_t)(k+1)*128+j]*cvec_s[128+k+1];
      a2 += WpT[(size_t)(k+2)*128+j]*cvec_s[128+k+2];
      a3 += WpT[(size_t)(k+3)*128+j]*cvec_s[128+k+3];
    }
    cpy_s[j] = (a0+a1)+(a2+a3) + bp[j];
  } else {
    const int j = tid-128;
    float a0=0.f,a1=0.f,a2=0.f,a3=0.f;
    for(int k=0;k<F;k+=4){
      a0 += Wpy[(size_t)(k+0)*128+j]*cvec_s[256+k+0];
      a1 += Wpy[(size_t)(k+1)*128+j]*cvec_s[256+k+1];
      a2 += Wpy[(size_t)(k+2)*128+j]*cvec_s[256+k+2];
      a3 += Wpy[(size_t)(k+3)*128+j]*cvec_s[256+k+3];
    }
    vz[b*F+j] = (a0+a1)+(a2+a3);
  }
  __syncthreads();
  if(tid<128){
    const int j = tid;
    float a0=0.f,a1=0.f,a2=0.f,a3=0.f;
    for(int k=0;k<F;k+=4){
      a0 += Wc[(size_t)(256+k+0)*256 + 128 + j]*cpy_s[k+0];
      a1 += Wc[(size_t)(256+k+1)*256 + 128 + j]*cpy_s[k+1];
      a2 += Wc[(size_t)(256+k+2)*256 + 128 + j]*cpy_s[k+2];
      a3 += Wc[(size_t)(256+k+3)*256 + 128 + j]*cpy_s[k+3];
    }
    czc[b*F+j] = (a0+a1)+(a2+a3);
  } else if(tid<192){
    const int lane = tid-128;
    float p = cpy_s[lane]*cvec_s[256+lane] + cpy_s[64+lane]*cvec_s[256+64+lane];
    p = wsum(p);
    if(lane==0) szc[b]=p;
  }
}

// K2c: per (agent a, batch b): af (WaT), afx, sx
__global__ __launch_bounds__(256) void k2c_agents(
    const float* __restrict__ nf, const float* __restrict__ WaT, const float* __restrict__ ba,
    const float* __restrict__ Wc,
    const float* __restrict__ deglb_g, const float* __restrict__ fa_g, const float* __restrict__ cx,
    float* __restrict__ afx, float* __restrict__ sx){
  const int a = blockIdx.x, b = blockIdx.y, tid = threadIdx.x;
  __shared__ float src_s[384];
  __shared__ float af_s[F], cx_s[F];
  if(tid<128){ src_s[tid] = deglb_g[b*F+tid]; cx_s[tid]=cx[b*F+tid]; }
  else if(a<16){
    const int j = tid-128;
    src_s[128+j] = nf[(size_t)(b*F+j)*NTOT + CN + a];
    src_s[256+j] = nf[(size_t)(b*F+j)*NTOT + CN + AN + a];
  }
  __syncthreads();
  if(a<16){
    if(tid<128){
      const int j = tid;
      float a0=0.f,a1=0.f,a2=0.f,a3=0.f;
      for(int k=0;k<384;k+=4){
        a0 += WaT[(size_t)(k+0)*128+j]*src_s[k+0];
        a1 += WaT[(size_t)(k+1)*128+j]*src_s[k+1];
        a2 += WaT[(size_t)(k+2)*128+j]*src_s[k+2];
        a3 += WaT[(size_t)(k+3)*128+j]*src_s[k+3];
      }
      af_s[j] = (a0+a1)+(a2+a3) + ba[j];
    }
  } else if(tid<128){
    af_s[tid] = fa_g[b*F+tid];
  }
  __syncthreads();
  if(tid<128){
    const int j = tid;
    float a0=0.f,a1=0.f,a2=0.f,a3=0.f;
    for(int i=0;i<F;i+=4){
      a0 += af_s[i+0]*Wc[(size_t)(i+0)*256 + 128 + j];
      a1 += af_s[i+1]*Wc[(size_t)(i+1)*256 + 128 + j];
      a2 += af_s[i+2]*Wc[(size_t)(i+2)*256 + 128 + j];
      a3 += af_s[i+3]*Wc[(size_t)(i+3)*256 + 128 + j];
    }
    afx[((size_t)b*NA+a)*F + j] = (a0+a1)+(a2+a3);
  } else if(tid<192){
    const int lane = tid-128;
    float p = af_s[lane]*cx_s[lane] + af_s[64+lane]*cx_s[64+lane];
    p = wsum(p);
    if(lane==0) sx[b*NA+a]=p;
  }
}

// K35: fused scores + chunk softmax + t-accum. 512 threads, CHK=256.
// phase1: kq = wave-pair K-quarter (parallel pairwise combine), 2 cities/thread.
// phase4: 2 features x 9 agents x 4-way g-parity.
__global__ __launch_bounds__(512) void k35_flash(const float* __restrict__ nf,
      const float* __restrict__ afx, const float* __restrict__ sx,
      float* __restrict__ pmax, float* __restrict__ psum, float* __restrict__ tpart){
  const int b = blockIdx.y, tid = threadIdx.x;
  const int chunk = blockIdx.x, c0 = chunk*CHK;
  __shared__ float afx_s[NA*F];        // 8.7 KB (reused in phase-4 combine)
  __shared__ float sx_s[NA];
  __shared__ float at_s[NA*CHK];       // 17.4 KB
  __shared__ float at2_s[2*NA*CHK];    // 34.8 KB (phase-1 combine slots; phase-4 pt0/pt1)
  __shared__ float4 nf4_s[F*8];        // 16 KB
  __shared__ float red_s[8][NA], red2_s[8][NA];
  for(int o=tid;o<NA*F;o+=512) afx_s[o]=afx[(size_t)b*NA*F+o];
  if(tid<NA) sx_s[tid]=sx[b*NA+tid];
  __syncthreads();
  const int kq = tid>>7, cl = tid&127;
  // ---- phase 1: 2 cities (cl, cl+128) x 17 agents x 32-K ----
  float a0v[NA], a1v[NA];
  #pragma unroll
  for(int a=0;a<NA;a++){ a0v[a]=0.f; a1v[a]=0.f; }
  {
    const float* base = nf + (size_t)b*F*NTOT + (size_t)(kq*32)*NTOT + c0 + cl;
    #pragma unroll 2
    for(int q=0;q<8;q++){
      const float* r0 = base + (size_t)(q*4)*NTOT;
      float v0 = r0[0],      u0 = r0[128];
      float v1 = r0[NTOT],   u1 = r0[NTOT+128];
      float v2 = r0[2*NTOT], u2 = r0[2*NTOT+128];
      float v3 = r0[3*NTOT], u3 = r0[3*NTOT+128];
      #pragma unroll
      for(int a=0;a<NA;a++){
        float4 wv = *(const float4*)&afx_s[a*F + kq*32 + q*4];
        a0v[a] += wv.x*v0 + wv.y*v1 + wv.z*v2 + wv.w*v3;
        a1v[a] += wv.x*u0 + wv.y*u1 + wv.z*u2 + wv.w*u3;
      }
    }
  }
  // pairwise K-quarter combine: (1->slot0, 3->slot1), (0+=slot0, 2+=slot1->at_s), (0+=at_s)
  if(kq==1){
    #pragma unroll
    for(int a=0;a<NA;a++){ at2_s[a*CHK+cl]=a0v[a]; at2_s[a*CHK+cl+128]=a1v[a]; }
  } else if(kq==3){
    #pragma unroll
    for(int a=0;a<NA;a++){ at2_s[NA*CHK+a*CHK+cl]=a0v[a]; at2_s[NA*CHK+a*CHK+cl+128]=a1v[a]; }
  }
  __syncthreads();
  if(kq==0){
    #pragma unroll
    for(int a=0;a<NA;a++){ a0v[a]+=at2_s[a*CHK+cl]; a1v[a]+=at2_s[a*CHK+cl+128]; }
  } else if(kq==2){
    #pragma unroll
    for(int a=0;a<NA;a++){
      at_s[a*CHK+cl]     = a0v[a]+at2_s[NA*CHK+a*CHK+cl];
      at_s[a*CHK+cl+128] = a1v[a]+at2_s[NA*CHK+a*CHK+cl+128];
    }
  }
  __syncthreads();
  const float scale = 0.088388347648318447f;
  if(kq==0){
    #pragma unroll
    for(int a=0;a<NA;a++){
      at_s[a*CHK+cl]     = (a0v[a]+at_s[a*CHK+cl]+sx_s[a])*scale;
      at_s[a*CHK+cl+128] = (a1v[a]+at_s[a*CHK+cl+128]+sx_s[a])*scale;
    }
  }
  __syncthreads();
  // ---- softmax over chunk: agent-split halves, thread = 1 city ----
  const int w = tid>>6;
  const int hh = tid>>8, c = tid&255;
  const int aBeg = hh? 9:0;
  const int lane = tid&63;
  float sc[9];
  #pragma unroll
  for(int a2=0;a2<9;a2++){
    const int a = aBeg+a2;
    if(a<NA){
      sc[a2] = at_s[a*CHK+c];
      float mx = wmax(sc[a2]);
      if(lane==0) red_s[w][a]=mx;
    }
  }
  __syncthreads();
  #pragma unroll
  for(int a2=0;a2<9;a2++){
    const int a = aBeg+a2;
    if(a<NA){
      const int rb = hh*4;
      float m = fmaxf(fmaxf(red_s[rb][a],red_s[rb+1][a]), fmaxf(red_s[rb+2][a],red_s[rb+3][a]));
      float e = __expf(sc[a2]-m);
      at_s[a*CHK+c] = e;
      float s = wsum(e);
      if(lane==0) red2_s[w][a]=s;
    }
  }
  __syncthreads();
  if(tid<NA){
    const int rb = (tid<9)? 0 : 4;
    pmax[(b*NA+tid)*NCHK + chunk] =
      fmaxf(fmaxf(red_s[rb][tid],red_s[rb+1][tid]), fmaxf(red_s[rb+2][tid],red_s[rb+3][tid]));
    psum[(b*NA+tid)*NCHK + chunk] =
      red2_s[rb][tid]+red2_s[rb+1][tid]+red2_s[rb+2][tid]+red2_s[rb+3][tid];
  }
  // ---- phase 4: tpart[a][i] = sum_c e[a,c]*nf[i,c] ----
  const int i1 = tid&63;
  const int gpar = (tid>>6)&3;
  const int h = tid>>8, A0 = h*8;
  float ta0[9], ta1[9];
  #pragma unroll
  for(int a=0;a<9;a++){ ta0[a]=0.f; ta1[a]=0.f; }
  for(int s8=0;s8<8;s8++){
    const int csl = s8*32, cs = c0 + csl;
    __syncthreads();
    for(int idx=tid; idx<F*8; idx+=512){
      const int ii=idx>>3, g=idx&7;
      nf4_s[ii*8 + (g^(ii&7))] = *(const float4*)(nf + (size_t)(b*F+ii)*NTOT + cs + g*4);
    }
    __syncthreads();
    #pragma unroll
    for(int gg=0; gg<2; gg++){
      const int g = gg*4 + gpar;
      float4 v0 = nf4_s[i1*8 + (g^(i1&7))];
      float4 v1 = nf4_s[(i1+64)*8 + (g^(i1&7))];
      #pragma unroll
      for(int a=0;a<9;a++){
        float4 wv = *(const float4*)&at_s[(A0+a)*CHK + csl + g*4];
        ta0[a] += wv.x*v0.x + wv.y*v0.y + wv.z*v0.z + wv.w*v0.w;
        ta1[a] += wv.x*v1.x + wv.y*v1.y + wv.z*v1.z + wv.w*v1.w;
      }
    }
  }
  // combine 4 g-parities: pt0/pt1 in at2_s, gpar2 sum via afx_s, gpar0 writes out
  float* pt0 = at2_s;
  float* pt1 = at2_s + NA*F;
  __syncthreads();
  if(gpar==1){
    #pragma unroll
    for(int a=0;a<9;a++){ pt0[(A0+a)*F+i1]=ta0[a]; pt0[(A0+a)*F+i1+64]=ta1[a]; }
  } else if(gpar==3){
    #pragma unroll
    for(int a=0;a<9;a++){ pt1[(A0+a)*F+i1]=ta0[a]; pt1[(A0+a)*F+i1+64]=ta1[a]; }
  }
  __syncthreads();
  if(gpar==2){
    #pragma unroll
    for(int a=0;a<9;a++){
      afx_s[(A0+a)*F+i1]    = ta0[a]+pt1[(A0+a)*F+i1];
      afx_s[(A0+a)*F+i1+64] = ta1[a]+pt1[(A0+a)*F+i1+64];
    }
  } else if(gpar==0){
    #pragma unroll
    for(int a=0;a<9;a++){ ta0[a]+=pt0[(A0+a)*F+i1]; ta1[a]+=pt0[(A0+a)*F+i1+64]; }
  }
  __syncthreads();
  if(gpar==0){
    float* dst = tpart + (size_t)chunk*64*NA*F + (size_t)b*NA*F;
    #pragma unroll
    for(int a=0;a<9;a++){
      if(h==0 || a>0){
        dst[(A0+a)*F+i1]    = ta0[a]+afx_s[(A0+a)*F+i1];
        dst[(A0+a)*F+i1+64] = ta1[a]+afx_s[(A0+a)*F+i1+64];
      }
    }
  }
}

// K5c: per (b,a): combine 8 chunks with rescale; tn; afz = M1@tn + czc; sz = tn.vz + szc
__global__ __launch_bounds__(128) void k5c_final(const float* __restrict__ M1,
      const float* __restrict__ tpart, const float* __restrict__ pmax, const float* __restrict__ psum,
      const float* __restrict__ czc, const float* __restrict__ vz, const float* __restrict__ szc,
      float* __restrict__ afz, float* __restrict__ szv){
  const int a = blockIdx.x, b = blockIdx.y, tid = threadIdx.x;
  __shared__ float tn_s[F];
  const float* pm = pmax + (b*NA+a)*NCHK;
  const float* ps = psum + (b*NA+a)*NCHK;
  float M=-INFINITY;
  #pragma unroll
  for(int k=0;k<NCHK;k++) M = fmaxf(M, pm[k]);
  float w[NCHK]; float rs=0.f;
  #pragma unroll
  for(int k=0;k<NCHK;k++){ w[k]=__expf(pm[k]-M); rs += ps[k]*w[k]; }
  float s = 0.f;
  #pragma unroll
  for(int k=0;k<NCHK;k++) s += tpart[(size_t)k*64*NA*F + ((size_t)b*NA+a)*F + tid]*w[k];
  tn_s[tid] = s / rs;
  __syncthreads();
  float acc = 0.f;
  const float* m = M1 + (size_t)tid*F;
  for(int i=0;i<F;i++) acc += m[i]*tn_s[i];
  afz[((size_t)b*NA+a)*F + tid] = acc + czc[b*F+tid];
  float p = tn_s[tid]*vz[b*F+tid];
  p = wsum(p);
  __shared__ float red[2];
  if((tid&63)==0) red[tid>>6]=p;
  __syncthreads();
  if(tid==0) szv[b*NA+a] = red[0]+red[1] + szc[b];
}

// K6: logits + tanh + agent softmax. 512 threads, CHK=256, same phase-1 as k35.
__global__ __launch_bounds__(512) void k6_out(const float* __restrict__ nf, const float* __restrict__ afz,
      const float* __restrict__ szv, const int* __restrict__ step, float* __restrict__ out){
  const int b = blockIdx.y, tid = threadIdx.x;
  const int chunk = blockIdx.x, c0 = chunk*CHK;
  __shared__ float afz_s[NA*F];
  __shared__ float sz_s[NA];
  __shared__ float at_s[NA*CHK];
  __shared__ float at2_s[2*NA*CHK];
  for(int o=tid;o<NA*F;o+=512) afz_s[o]=afz[(size_t)b*NA*F+o];
  if(tid<NA) sz_s[tid]=szv[b*NA+tid];
  __syncthreads();
  const int kq = tid>>7, cl = tid&127;
  float a0v[NA], a1v[NA];
  #pragma unroll
  for(int a=0;a<NA;a++){ a0v[a]=0.f; a1v[a]=0.f; }
  {
    const float* base = nf + (size_t)b*F*NTOT + (size_t)(kq*32)*NTOT + c0 + cl;
    #pragma unroll 2
    for(int q=0;q<8;q++){
      const float* r0 = base + (size_t)(q*4)*NTOT;
      float v0 = r0[0],      u0 = r0[128];
      float v1 = r0[NTOT],   u1 = r0[NTOT+128];
      float v2 = r0[2*NTOT], u2 = r0[2*NTOT+128];
      float v3 = r0[3*NTOT], u3 = r0[3*NTOT+128];
      #pragma unroll
      for(int a=0;a<NA;a++){
        float4 wv = *(const float4*)&afz_s[a*F + kq*32 + q*4];
        a0v[a] += wv.x*v0 + wv.y*v1 + wv.z*v2 + wv.w*v3;
        a1v[a] += wv.x*u0 + wv.y*u1 + wv.z*u2 + wv.w*u3;
      }
    }
  }
  if(kq==1){
    #pragma unroll
    for(int a=0;a<NA;a++){ at2_s[a*CHK+cl]=a0v[a]; at2_s[a*CHK+cl+128]=a1v[a]; }
  } else if(kq==3){
    #pragma unroll
    for(int a=0;a<NA;a++){ at2_s[NA*CHK+a*CHK+cl]=a0v[a]; at2_s[NA*CHK+a*CHK+cl+128]=a1v[a]; }
  }
  __syncthreads();
  if(kq==0){
    #pragma unroll
    for(int a=0;a<NA;a++){ a0v[a]+=at2_s[a*CHK+cl]; a1v[a]+=at2_s[a*CHK+cl+128]; }
  } else if(kq==2){
    #pragma unroll
    for(int a=0;a<NA;a++){
      at_s[a*CHK+cl]     = a0v[a]+at2_s[NA*CHK+a*CHK+cl];
      at_s[a*CHK+cl+128] = a1v[a]+at2_s[NA*CHK+a*CHK+cl+128];
    }
  }
  __syncthreads();
  if(kq==0){
    #pragma unroll
    for(int a=0;a<NA;a++){
      at_s[a*CHK+cl]     += a0v[a];
      at_s[a*CHK+cl+128] += a1v[a];
    }
  }
  __syncthreads();
  if(tid<256){
    const int c = tid;
    const int A = (step[0] > 0) ? NA : AN;
    const float scale = 0.088388347648318447f;
    float l[NA];
    #pragma unroll
    for(int a=0;a<NA;a++)
      l[a] = tanhf((at_s[a*CHK+c] + sz_s[a])*scale)*10.f;
    const bool f17 = (A==NA);
    float m = l[0];
    #pragma unroll
    for(int a=1;a<AN;a++) m = fmaxf(m,l[a]);
    if(f17) m = fmaxf(m,l[16]);
    float ssum=0.f;
    #pragma unroll
    for(int a=0;a<AN;a++){ float e=__expf(l[a]-m); l[a]=e; ssum+=e; }
    float e16=__expf(l[16]-m);
    if(f17){ ssum+=e16; }
    const float inv = 1.f/ssum;
    float* op = out + (size_t)(b*CN + c0 + c)*A;
    #pragma unroll
    for(int a=0;a<AN;a++) op[a]=l[a]*inv;
    if(f17) op[16]=e16*inv;
  }
}

extern "C" void kernel_launch(void* const* d_in, const int* in_sizes, int n_in,
                              void* d_out, int out_size, void* d_ws, size_t ws_size,
                              hipStream_t stream){
  const float* nf = (const float*)d_in[0];
  const float* Wg = (const float*)d_in[1];
  const float* bg = (const float*)d_in[2];
  const float* Wc = (const float*)d_in[3];
  const float* bc = (const float*)d_in[4];
  const float* Wa = (const float*)d_in[5];
  const float* ba = (const float*)d_in[6];
  const float* Wp = (const float*)d_in[7];
  const float* bp = (const float*)d_in[8];
  const int*  step = (const int*)d_in[9];
  float* out = (float*)d_out;

  float* ws = (float*)d_ws;
  float* glb     = ws;                    // 64*512
  float* ave     = glb + 64*512;          // 64*512
  float* afx     = ave + 64*512;          // 64*17*128
  float* sx      = afx + 64*NA*F;         // 64*17
  float* Wpy     = sx + 64*NA;            // 128*128
  float* M1      = Wpy + F*F;             // 128*128
  float* czc     = M1 + F*F;              // 64*128
  float* vz      = czc + 64*F;            // 64*128
  float* szc     = vz + 64*F;             // 64
  float* pmax    = szc + 64;              // 64*17*8
  float* psum    = pmax + 64*NA*NCHK;     // 64*17*8
  float* deglb_g = psum + 64*NA*NCHK;     // 64*128
  float* fa_g    = deglb_g + 64*F;        // 64*128
  float* cx      = fa_g + 64*F;           // 64*128
  float* WgT     = cx + 64*F;             // 512*128
  float* WcT     = WgT + 512*F;           // 256*384
  float* WpT     = WcT + 256*384;         // 128*128
  float* WaT     = WpT + F*F;             // 384*128
  float* tpart   = WaT + 384*F;           // 8*64*17*128
  float* afz     = tpart + (size_t)NCHK*64*NA*F;  // 64*17*128
  float* szv     = afz + 64*NA*F;         // 64*17

  k0t_transpose<<<dim3(16,12,4),256,0,stream>>>(Wg,Wc,Wp,Wa, WgT,WcT,WpT,WaT);
  k0a_wpy<<<F,F,0,stream>>>(Wp, Wc, Wpy);
  k0b_m1<<<F,F,0,stream>>>(Wc, Wpy, M1);
  k1_reduce<<<dim3(32,64),256,0,stream>>>(nf, glb, ave);
  k2a_prep<<<64,256,0,stream>>>(WgT,bg, WcT,Wc,bc, WpT,bp, Wpy, glb,ave, deglb_g,fa_g,cx, czc,vz,szc);
  k2c_agents<<<dim3(NA,64),256,0,stream>>>(nf, WaT,ba,Wc, deglb_g,fa_g,cx, afx,sx);
  k35_flash<<<dim3(NCHK,64),512,0,stream>>>(nf, afx, sx, pmax, psum, tpart);
  k5c_final<<<dim3(NA,64),128,0,stream>>>(M1, tpart, pmax, psum, czc, vz, szc, afz, szv);
  k6_out<<<dim3(NCHK,64),512,0,stream>>>(nf, afz, szv, step, out);
}

// Round 10
// 156.679 us; speedup vs baseline: 1.0362x; 1.0220x over previous
//
#include <hip/hip_runtime.h>
#include <math.h>

#define F 128
#define NTOT 2080
#define CN 2048
#define AN 16
#define NA 17   // max agents (step>0)
#define CHK 256 // cities per chunk (k35/k6)
#define NCHK 8  // CN/CHK

__device__ __forceinline__ float wmax(float v){
  #pragma unroll
  for(int m=32;m;m>>=1) v = fmaxf(v, __shfl_xor(v, m, 64));
  return v;
}
__device__ __forceinline__ float wsum(float v){
  #pragma unroll
  for(int m=32;m;m>>=1) v += __shfl_xor(v, m, 64);
  return v;
}

// K0t: tiled transposes of Wg(128x512), Wc(384x256), Wp(128x128), Wa(128x384)
__global__ __launch_bounds__(256) void k0t_transpose(
      const float* __restrict__ Wg, const float* __restrict__ Wc,
      const float* __restrict__ Wp, const float* __restrict__ Wa,
      float* __restrict__ WgT, float* __restrict__ WcT,
      float* __restrict__ WpT, float* __restrict__ WaT){
  __shared__ float tile[32][33];
  const int z = blockIdx.z;
  const float* src; float* dst; int R, C;
  if(z==0){ src=Wg; dst=WgT; R=128; C=512; }
  else if(z==1){ src=Wc; dst=WcT; R=384; C=256; }
  else if(z==2){ src=Wp; dst=WpT; R=128; C=128; }
  else { src=Wa; dst=WaT; R=128; C=384; }
  const int c0 = blockIdx.x*32, r0 = blockIdx.y*32;
  if(c0>=C || r0>=R) return;
  const int tx = threadIdx.x&31, ty = threadIdx.x>>5;   // 32x8
  #pragma unroll
  for(int rr=0;rr<4;rr++)
    tile[ty+rr*8][tx] = src[(size_t)(r0+ty+rr*8)*C + c0 + tx];
  __syncthreads();
  #pragma unroll
  for(int rr=0;rr<4;rr++)
    dst[(size_t)(c0+ty+rr*8)*R + r0 + tx] = tile[tx][ty+rr*8];
}

// K0a: Wpy = Wp @ Wcy2
__global__ __launch_bounds__(128) void k0a_wpy(const float* __restrict__ Wp, const float* __restrict__ Wc,
                                               float* __restrict__ Wpy){
  const int k = blockIdx.x, i = threadIdx.x;
  float acc = 0.f;
  const float* wp = Wp + (size_t)k*F;
  for(int j=0;j<F;j++) acc += wp[j]*Wc[(size_t)(128+j)*256 + 128 + i];
  Wpy[k*F+i] = acc;
}

// K0b: M1 = Wcz2^T @ Wpy
__global__ __launch_bounds__(128) void k0b_m1(const float* __restrict__ Wc, const float* __restrict__ Wpy,
                                              float* __restrict__ M1){
  const int jc = blockIdx.x, i = threadIdx.x;
  float acc = 0.f;
  for(int k=0;k<F;k++) acc += Wc[(size_t)(256+k)*256 + 128 + jc]*Wpy[k*F+i];
  M1[jc*F+i] = acc;
}

// K1: per (b, j-group of 4): one wave per feature row, segment max/mean over N=2080
__global__ __launch_bounds__(256) void k1_reduce(const float* __restrict__ nf,
                                                 float* __restrict__ glb, float* __restrict__ ave){
  const int jg = blockIdx.x, b = blockIdx.y;
  const int w = threadIdx.x>>6, lane = threadIdx.x&63;
  const int j = jg*4 + w;
  const float4* row = (const float4*)(nf + (size_t)(b*F + j)*NTOT);
  float cmax=-INFINITY, csum=0.f, smax=-INFINITY, ssum=0.f, emax=-INFINITY, esum=0.f;
  for(int n4 = lane; n4 < 520; n4 += 64){
    float4 v = row[n4];
    float mx = fmaxf(fmaxf(v.x,v.y), fmaxf(v.z,v.w));
    float sm = (v.x+v.y)+(v.z+v.w);
    if(n4 < 512){ cmax=fmaxf(cmax,mx); csum+=sm; }
    else if(n4 < 516){ smax=fmaxf(smax,mx); ssum+=sm; }
    else { emax=fmaxf(emax,mx); esum+=sm; }
  }
  cmax=wmax(cmax); csum=wsum(csum); smax=wmax(smax); ssum=wsum(ssum); emax=wmax(emax); esum=wsum(esum);
  if(lane==0){
    const int gb = b*4*F;
    glb[gb + j]       = fmaxf(cmax, fmaxf(smax,emax));
    glb[gb + F + j]   = cmax;
    glb[gb + 2*F + j] = smax;
    glb[gb + 3*F + j] = emax;
    float tS = csum+ssum+esum;
    ave[gb + j]       = tS / 2080.f;
    ave[gb + F + j]   = csum / 2048.f;
    ave[gb + 2*F + j] = ssum / 16.f;
    ave[gb + 3*F + j] = esum / 16.f;
  }
}

// K2a: per-batch small matvecs (transposed weights, thread-per-output)
__global__ __launch_bounds__(256) void k2a_prep(
    const float* __restrict__ WgT, const float* __restrict__ bg,
    const float* __restrict__ WcT, const float* __restrict__ Wc, const float* __restrict__ bc,
    const float* __restrict__ WpT, const float* __restrict__ bp,
    const float* __restrict__ Wpy,
    const float* __restrict__ glb, const float* __restrict__ ave,
    float* __restrict__ deglb_g, float* __restrict__ fa_g, float* __restrict__ cx,
    float* __restrict__ czc, float* __restrict__ vz, float* __restrict__ szc){
  const int b = blockIdx.x, tid = threadIdx.x;
  __shared__ float glb_s[512], ave_s[512];
  __shared__ float deglb_s[F], cvec_s[3*F], cpy_s[F];
  for(int i=tid;i<512;i+=256){ glb_s[i]=glb[b*512+i]; ave_s[i]=ave[b*512+i]; }
  __syncthreads();
  {
    const int j = tid&127;
    const float* src = (tid<128)? glb_s : ave_s;
    float a0=0.f,a1=0.f,a2=0.f,a3=0.f;
    for(int k=0;k<512;k+=4){
      a0 += WgT[(size_t)(k+0)*128+j]*src[k+0];
      a1 += WgT[(size_t)(k+1)*128+j]*src[k+1];
      a2 += WgT[(size_t)(k+2)*128+j]*src[k+2];
      a3 += WgT[(size_t)(k+3)*128+j]*src[k+3];
    }
    float d = (a0+a1)+(a2+a3) + bg[j];
    if(tid<128){ deglb_s[j]=d; deglb_g[b*F+j]=d; }
    else fa_g[b*F+j]=d;
  }
  __syncthreads();
  for(int i=tid;i<3*F;i+=256){
    float a0=0.f,a1=0.f,a2=0.f,a3=0.f;
    for(int k=0;k<F;k+=4){
      a0 += WcT[(size_t)(k+0)*384+i]*deglb_s[k+0];
      a1 += WcT[(size_t)(k+1)*384+i]*deglb_s[k+1];
      a2 += WcT[(size_t)(k+2)*384+i]*deglb_s[k+2];
      a3 += WcT[(size_t)(k+3)*384+i]*deglb_s[k+3];
    }
    float v = (a0+a1)+(a2+a3) + bc[i];
    cvec_s[i]=v;
    if(i<F) cx[b*F+i]=v;
  }
  __syncthreads();
  if(tid<128){
    const int j = tid;
    float a0=0.f,a1=0.f,a2=0.f,a3=0.f;
    for(int k=0;k<F;k+=4){
      a0 += WpT[(size_t)(k+0)*128+j]*cvec_s[128+k+0];
      a1 += WpT[(size_t)(k+1)*128+j]*cvec_s[128+k+1];
      a2 += WpT[(size_t)(k+2)*128+j]*cvec_s[128+k+2];
      a3 += WpT[(size_t)(k+3)*128+j]*cvec_s[128+k+3];
    }
    cpy_s[j] = (a0+a1)+(a2+a3) + bp[j];
  } else {
    const int j = tid-128;
    float a0=0.f,a1=0.f,a2=0.f,a3=0.f;
    for(int k=0;k<F;k+=4){
      a0 += Wpy[(size_t)(k+0)*128+j]*cvec_s[256+k+0];
      a1 += Wpy[(size_t)(k+1)*128+j]*cvec_s[256+k+1];
      a2 += Wpy[(size_t)(k+2)*128+j]*cvec_s[256+k+2];
      a3 += Wpy[(size_t)(k+3)*128+j]*cvec_s[256+k+3];
    }
    vz[b*F+j] = (a0+a1)+(a2+a3);
  }
  __syncthreads();
  if(tid<128){
    const int j = tid;
    float a0=0.f,a1=0.f,a2=0.f,a3=0.f;
    for(int k=0;k<F;k+=4){
      a0 += Wc[(size_t)(256+k+0)*256 + 128 + j]*cpy_s[k+0];
      a1 += Wc[(size_t)(256+k+1)*256 + 128 + j]*cpy_s[k+1];
      a2 += Wc[(size_t)(256+k+2)*256 + 128 + j]*cpy_s[k+2];
      a3 += Wc[(size_t)(256+k+3)*256 + 128 + j]*cpy_s[k+3];
    }
    czc[b*F+j] = (a0+a1)+(a2+a3);
  } else if(tid<192){
    const int lane = tid-128;
    float p = cpy_s[lane]*cvec_s[256+lane] + cpy_s[64+lane]*cvec_s[256+64+lane];
    p = wsum(p);
    if(lane==0) szc[b]=p;
  }
}

// K2c: per (agent a, batch b): af (WaT), afx, sx
__global__ __launch_bounds__(256) void k2c_agents(
    const float* __restrict__ nf, const float* __restrict__ WaT, const float* __restrict__ ba,
    const float* __restrict__ Wc,
    const float* __restrict__ deglb_g, const float* __restrict__ fa_g, const float* __restrict__ cx,
    float* __restrict__ afx, float* __restrict__ sx){
  const int a = blockIdx.x, b = blockIdx.y, tid = threadIdx.x;
  __shared__ float src_s[384];
  __shared__ float af_s[F], cx_s[F];
  if(tid<128){ src_s[tid] = deglb_g[b*F+tid]; cx_s[tid]=cx[b*F+tid]; }
  else if(a<16){
    const int j = tid-128;
    src_s[128+j] = nf[(size_t)(b*F+j)*NTOT + CN + a];
    src_s[256+j] = nf[(size_t)(b*F+j)*NTOT + CN + AN + a];
  }
  __syncthreads();
  if(a<16){
    if(tid<128){
      const int j = tid;
      float a0=0.f,a1=0.f,a2=0.f,a3=0.f;
      for(int k=0;k<384;k+=4){
        a0 += WaT[(size_t)(k+0)*128+j]*src_s[k+0];
        a1 += WaT[(size_t)(k+1)*128+j]*src_s[k+1];
        a2 += WaT[(size_t)(k+2)*128+j]*src_s[k+2];
        a3 += WaT[(size_t)(k+3)*128+j]*src_s[k+3];
      }
      af_s[j] = (a0+a1)+(a2+a3) + ba[j];
    }
  } else if(tid<128){
    af_s[tid] = fa_g[b*F+tid];
  }
  __syncthreads();
  if(tid<128){
    const int j = tid;
    float a0=0.f,a1=0.f,a2=0.f,a3=0.f;
    for(int i=0;i<F;i+=4){
      a0 += af_s[i+0]*Wc[(size_t)(i+0)*256 + 128 + j];
      a1 += af_s[i+1]*Wc[(size_t)(i+1)*256 + 128 + j];
      a2 += af_s[i+2]*Wc[(size_t)(i+2)*256 + 128 + j];
      a3 += af_s[i+3]*Wc[(size_t)(i+3)*256 + 128 + j];
    }
    afx[((size_t)b*NA+a)*F + j] = (a0+a1)+(a2+a3);
  } else if(tid<192){
    const int lane = tid-128;
    float p = af_s[lane]*cx_s[lane] + af_s[64+lane]*cx_s[64+lane];
    p = wsum(p);
    if(lane==0) sx[b*NA+a]=p;
  }
}

// K35: fused scores + chunk softmax + t-accum. CHK=256, 256 threads.
// phase1: thread = 2 cities (cl, cl+128) x 17 agents x K-half (h), R6's 2-step combine.
// phase4: R6 structure, 8 subtiles of 32 cities.
__global__ __launch_bounds__(256) void k35_flash(const float* __restrict__ nf,
      const float* __restrict__ afx, const float* __restrict__ sx,
      float* __restrict__ pmax, float* __restrict__ psum, float* __restrict__ tpart){
  const int b = blockIdx.y, tid = threadIdx.x;
  const int chunk = blockIdx.x, c0 = chunk*CHK;
  __shared__ float afx_s[NA*F];     // 8.7 KB
  __shared__ float sx_s[NA];
  __shared__ float at_s[NA*CHK];    // 17.4 KB
  __shared__ float4 nf4_s[F*8];     // 16 KB
  __shared__ float red_s[4][NA], red2_s[4][NA], m_s[NA];
  for(int o=tid;o<NA*F;o+=256) afx_s[o]=afx[(size_t)b*NA*F+o];
  if(tid<NA) sx_s[tid]=sx[b*NA+tid];
  __syncthreads();
  const int h = tid>>7, cl = tid&127, i0 = h*64;
  // ---- phase 1: 2 cities x 17 agents x 64-K (half) ----
  float a0v[NA], a1v[NA];
  #pragma unroll
  for(int a=0;a<NA;a++){ a0v[a]=0.f; a1v[a]=0.f; }
  {
    const float* base = nf + (size_t)b*F*NTOT + (size_t)i0*NTOT + c0 + cl;
    #pragma unroll 2
    for(int q=0;q<16;q++){
      const float* r = base + (size_t)(q*4)*NTOT;
      float v0 = r[0],      u0 = r[128];
      float v1 = r[NTOT],   u1 = r[NTOT+128];
      float v2 = r[2*NTOT], u2 = r[2*NTOT+128];
      float v3 = r[3*NTOT], u3 = r[3*NTOT+128];
      #pragma unroll
      for(int a=0;a<NA;a++){
        float4 wv = *(const float4*)&afx_s[a*F + i0 + q*4];
        a0v[a] += wv.x*v0 + wv.y*v1 + wv.z*v2 + wv.w*v3;
        a1v[a] += wv.x*u0 + wv.y*u1 + wv.z*u2 + wv.w*u3;
      }
    }
  }
  if(h==0){
    #pragma unroll
    for(int a=0;a<NA;a++){ at_s[a*CHK+cl]=a0v[a]; at_s[a*CHK+cl+128]=a1v[a]; }
  }
  __syncthreads();
  const float scale = 0.088388347648318447f;
  if(h==1){
    #pragma unroll
    for(int a=0;a<NA;a++){
      at_s[a*CHK+cl]     = (at_s[a*CHK+cl]     + a0v[a] + sx_s[a])*scale;
      at_s[a*CHK+cl+128] = (at_s[a*CHK+cl+128] + a1v[a] + sx_s[a])*scale;
    }
  }
  __syncthreads();
  // ---- softmax over chunk: thread = 1 city (c=tid), 17 agents ----
  const int lane = tid&63, w = tid>>6;
  float sc[NA];
  #pragma unroll
  for(int a=0;a<NA;a++){
    sc[a] = at_s[a*CHK+tid];
    float mx = wmax(sc[a]);
    if(lane==0) red_s[w][a]=mx;
  }
  __syncthreads();
  if(tid<NA){
    float m = fmaxf(fmaxf(red_s[0][tid],red_s[1][tid]), fmaxf(red_s[2][tid],red_s[3][tid]));
    m_s[tid]=m;
    pmax[(b*NA+tid)*NCHK + chunk]=m;
  }
  __syncthreads();
  #pragma unroll
  for(int a=0;a<NA;a++){
    float e = __expf(sc[a]-m_s[a]);
    at_s[a*CHK+tid]=e;
    float s = wsum(e);
    if(lane==0) red2_s[w][a]=s;
  }
  __syncthreads();
  if(tid<NA)
    psum[(b*NA+tid)*NCHK + chunk] =
      (red2_s[0][tid]+red2_s[1][tid])+(red2_s[2][tid]+red2_s[3][tid]);
  // ---- phase 4: tpart[a][i] = sum_c e[a,c]*nf[i,c], R6 structure, 8 subtiles ----
  const int i = tid&127, A0 = (tid>>7)*8;
  float ta[9];
  #pragma unroll
  for(int a=0;a<9;a++) ta[a]=0.f;
  for(int s8=0;s8<8;s8++){
    const int csl = s8*32, cs = c0 + csl;
    __syncthreads();
    for(int idx=tid; idx<F*8; idx+=256){
      const int ii=idx>>3, g=idx&7;
      nf4_s[ii*8 + (g^(ii&7))] = *(const float4*)(nf + (size_t)(b*F+ii)*NTOT + cs + g*4);
    }
    __syncthreads();
    #pragma unroll 2
    for(int g=0; g<8; g++){
      float4 v = nf4_s[i*8 + (g^(i&7))];
      #pragma unroll
      for(int a=0;a<9;a++){
        float4 wv = *(const float4*)&at_s[(A0+a)*CHK + csl + g*4];
        ta[a] += wv.x*v.x + wv.y*v.y + wv.z*v.z + wv.w*v.w;
      }
    }
  }
  float* dst = tpart + (size_t)chunk*64*NA*F + (size_t)b*NA*F;
  #pragma unroll
  for(int a=0;a<9;a++){
    if(tid<128 || a>0) dst[(A0+a)*F + i] = ta[a];
  }
}

// K5c: per (b,a): combine 8 chunks with rescale; tn; afz = M1@tn + czc; sz = tn.vz + szc
__global__ __launch_bounds__(128) void k5c_final(const float* __restrict__ M1,
      const float* __restrict__ tpart, const float* __restrict__ pmax, const float* __restrict__ psum,
      const float* __restrict__ czc, const float* __restrict__ vz, const float* __restrict__ szc,
      float* __restrict__ afz, float* __restrict__ szv){
  const int a = blockIdx.x, b = blockIdx.y, tid = threadIdx.x;
  __shared__ float tn_s[F];
  const float* pm = pmax + (b*NA+a)*NCHK;
  const float* ps = psum + (b*NA+a)*NCHK;
  float M=-INFINITY;
  #pragma unroll
  for(int k=0;k<NCHK;k++) M = fmaxf(M, pm[k]);
  float w[NCHK]; float rs=0.f;
  #pragma unroll
  for(int k=0;k<NCHK;k++){ w[k]=__expf(pm[k]-M); rs += ps[k]*w[k]; }
  float s = 0.f;
  #pragma unroll
  for(int k=0;k<NCHK;k++) s += tpart[(size_t)k*64*NA*F + ((size_t)b*NA+a)*F + tid]*w[k];
  tn_s[tid] = s / rs;
  __syncthreads();
  float acc = 0.f;
  const float* m = M1 + (size_t)tid*F;
  for(int i=0;i<F;i++) acc += m[i]*tn_s[i];
  afz[((size_t)b*NA+a)*F + tid] = acc + czc[b*F+tid];
  float p = tn_s[tid]*vz[b*F+tid];
  p = wsum(p);
  __shared__ float red[2];
  if((tid&63)==0) red[tid>>6]=p;
  __syncthreads();
  if(tid==0) szv[b*NA+a] = red[0]+red[1] + szc[b];
}

// K6: logits + tanh + agent softmax. CHK=256, phase1 = 2-city half-K like k35;
// epilogue thread = 1 city.
__global__ __launch_bounds__(256) void k6_out(const float* __restrict__ nf, const float* __restrict__ afz,
      const float* __restrict__ szv, const int* __restrict__ step, float* __restrict__ out){
  const int b = blockIdx.y, tid = threadIdx.x;
  const int chunk = blockIdx.x, c0 = chunk*CHK;
  __shared__ float afz_s[NA*F];
  __shared__ float sz_s[NA];
  __shared__ float at_s[NA*CHK];
  for(int o=tid;o<NA*F;o+=256) afz_s[o]=afz[(size_t)b*NA*F+o];
  if(tid<NA) sz_s[tid]=szv[b*NA+tid];
  __syncthreads();
  const int h = tid>>7, cl = tid&127, i0 = h*64;
  float a0v[NA], a1v[NA];
  #pragma unroll
  for(int a=0;a<NA;a++){ a0v[a]=0.f; a1v[a]=0.f; }
  {
    const float* base = nf + (size_t)b*F*NTOT + (size_t)i0*NTOT + c0 + cl;
    #pragma unroll 2
    for(int q=0;q<16;q++){
      const float* r = base + (size_t)(q*4)*NTOT;
      float v0 = r[0],      u0 = r[128];
      float v1 = r[NTOT],   u1 = r[NTOT+128];
      float v2 = r[2*NTOT], u2 = r[2*NTOT+128];
      float v3 = r[3*NTOT], u3 = r[3*NTOT+128];
      #pragma unroll
      for(int a=0;a<NA;a++){
        float4 wv = *(const float4*)&afz_s[a*F + i0 + q*4];
        a0v[a] += wv.x*v0 + wv.y*v1 + wv.z*v2 + wv.w*v3;
        a1v[a] += wv.x*u0 + wv.y*u1 + wv.z*u2 + wv.w*u3;
      }
    }
  }
  if(h==0){
    #pragma unroll
    for(int a=0;a<NA;a++){ at_s[a*CHK+cl]=a0v[a]; at_s[a*CHK+cl+128]=a1v[a]; }
  }
  __syncthreads();
  if(h==1){
    #pragma unroll
    for(int a=0;a<NA;a++){
      at_s[a*CHK+cl]     += a0v[a];
      at_s[a*CHK+cl+128] += a1v[a];
    }
  }
  __syncthreads();
  {
    const int c = tid;
    const int A = (step[0] > 0) ? NA : AN;
    const float scale = 0.088388347648318447f;
    float l[NA];
    #pragma unroll
    for(int a=0;a<NA;a++)
      l[a] = tanhf((at_s[a*CHK+c] + sz_s[a])*scale)*10.f;
    const bool f17 = (A==NA);
    float m = l[0];
    #pragma unroll
    for(int a=1;a<AN;a++) m = fmaxf(m,l[a]);
    if(f17) m = fmaxf(m,l[16]);
    float ssum=0.f;
    #pragma unroll
    for(int a=0;a<AN;a++){ float e=__expf(l[a]-m); l[a]=e; ssum+=e; }
    float e16=__expf(l[16]-m);
    if(f17){ ssum+=e16; }
    const float inv = 1.f/ssum;
    float* op = out + (size_t)(b*CN + c0 + c)*A;
    #pragma unroll
    for(int a=0;a<AN;a++) op[a]=l[a]*inv;
    if(f17) op[16]=e16*inv;
  }
}

extern "C" void kernel_launch(void* const* d_in, const int* in_sizes, int n_in,
                              void* d_out, int out_size, void* d_ws, size_t ws_size,
                              hipStream_t stream){
  const float* nf = (const float*)d_in[0];
  const float* Wg = (const float*)d_in[1];
  const float* bg = (const float*)d_in[2];
  const float* Wc = (const float*)d_in[3];
  const float* bc = (const float*)d_in[4];
  const float* Wa = (const float*)d_in[5];
  const float* ba = (const float*)d_in[6];
  const float* Wp = (const float*)d_in[7];
  const float* bp = (const float*)d_in[8];
  const int*  step = (const int*)d_in[9];
  float* out = (float*)d_out;

  float* ws = (float*)d_ws;
  float* glb     = ws;                    // 64*512
  float* ave     = glb + 64*512;          // 64*512
  float* afx     = ave + 64*512;          // 64*17*128
  float* sx      = afx + 64*NA*F;         // 64*17
  float* Wpy     = sx + 64*NA;            // 128*128
  float* M1      = Wpy + F*F;             // 128*128
  float* czc     = M1 + F*F;              // 64*128
  float* vz      = czc + 64*F;            // 64*128
  float* szc     = vz + 64*F;             // 64
  float* pmax    = szc + 64;              // 64*17*8
  float* psum    = pmax + 64*NA*NCHK;     // 64*17*8
  float* deglb_g = psum + 64*NA*NCHK;     // 64*128
  float* fa_g    = deglb_g + 64*F;        // 64*128
  float* cx      = fa_g + 64*F;           // 64*128
  float* WgT     = cx + 64*F;             // 512*128
  float* WcT     = WgT + 512*F;           // 256*384
  float* WpT     = WcT + 256*384;         // 128*128
  float* WaT     = WpT + F*F;             // 384*128
  float* tpart   = WaT + 384*F;           // 8*64*17*128
  float* afz     = tpart + (size_t)NCHK*64*NA*F;  // 64*17*128
  float* szv     = afz + 64*NA*F;         // 64*17

  k0t_transpose<<<dim3(16,12,4),256,0,stream>>>(Wg,Wc,Wp,Wa, WgT,WcT,WpT,WaT);
  k0a_wpy<<<F,F,0,stream>>>(Wp, Wc, Wpy);
  k0b_m1<<<F,F,0,stream>>>(Wc, Wpy, M1);
  k1_reduce<<<dim3(32,64),256,0,stream>>>(nf, glb, ave);
  k2a_prep<<<64,256,0,stream>>>(WgT,bg, WcT,Wc,bc, WpT,bp, Wpy, glb,ave, deglb_g,fa_g,cx, czc,vz,szc);
  k2c_agents<<<dim3(NA,64),256,0,stream>>>(nf, WaT,ba,Wc, deglb_g,fa_g,cx, afx,sx);
  k35_flash<<<dim3(NCHK,64),256,0,stream>>>(nf, afx, sx, pmax, psum, tpart);
  k5c_final<<<dim3(NA,64),128,0,stream>>>(M1, tpart, pmax, psum, czc, vz, szc, afz, szv);
  k6_out<<<dim3(NCHK,64),256,0,stream>>>(nf, afz, szv, step, out);
}